// Round 7
// baseline (369.522 us; speedup 1.0000x reference)
//
#include <hip/hip_runtime.h>

namespace {

constexpr int T = 32, H = 56, W = 56;
constexpr int HW = H * W;           // 3136
constexpr int THW = T * HW;
constexpr int PLANE_B = HW * 4;     // 12544 bytes per plane
constexpr int ROW_B = W * 4;        // 224 bytes per row

template <int N> struct ic { static constexpr int value = N; };

typedef int v4i __attribute__((ext_vector_type(4)));

// CK-style direct intrinsic bindings: compiler tracks these loads (auto waitcnt).
__device__ float buf_load_f32(v4i srd, int voff, int soff, int aux)
    __asm("llvm.amdgcn.raw.buffer.load.f32");
__device__ void buf_store_f32(float v, v4i srd, int voff, int soff, int aux)
    __asm("llvm.amdgcn.raw.buffer.store.f32");

__device__ __forceinline__ v4i make_srd(const void* p, int nrec) {
    v4i r;
    r.x = (int)(unsigned long long)p;
    r.y = (int)((unsigned long long)p >> 32);  // stride=0 in high half
    r.z = nrec;                                // num_records = BYTES (stride 0)
    r.w = 0x00020000;                          // raw untyped dword access
    return r;
}

__device__ __forceinline__ float sigm(float x) {
    // 1/(1+e^-x); fast native exp + rcp (rel err ~1e-6, threshold is 1.9e-2)
    float e = __expf(-x);
    return __builtin_amdgcn_rcpf(1.0f + e);
}

template <int P, int N, typename F>
__device__ __forceinline__ void unroll_for(F&& f) {
    if constexpr (P < N) { f(ic<P>{}); unroll_for<P + 1, N>(f); }
}

// Streaming scatter formulation (numerics proven in R4): each input plane p is
// loaded once (3x3 / thread via buffer loads, hardware-OOB halo), its 9 taps
// scatter into pending per-output accumulator rings; output t emits at p=t+3.
// R4's failure was preloading 81 weights into per-thread arrays -> VGPR live
// set ~130 vs cap 32 -> 400 MB scratch spill. Fix: weights read AT USE SITES
// through block-uniform pointers -> scalar K$-cached s_loads, zero VGPR cost.
// VGPR-budget law (R1-R6): compiler cap = 512/(2*min_waves); pin 3 -> cap 85
// (safe >> ~50 live floats); HW occupancy bins by ACTUAL count (<=64 -> 8/SIMD).
__global__ __launch_bounds__(256, 3)
void tts_fused(const float* __restrict__ x,
               const float* __restrict__ w1, const float* __restrict__ b1,
               const float* __restrict__ w2, const float* __restrict__ b2,
               const float* __restrict__ w3, const float* __restrict__ b3,
               const float* __restrict__ wm,
               float* __restrict__ out) {
    const int g = blockIdx.x * 256 + threadIdx.x;   // pixel index in plane
    if (g >= HW) return;                            // no barriers -> safe exit
    const int bc = blockIdx.y;                      // b*64 + c (block-uniform)
    const int h = g / W;
    const int w = g - h * W;

    const float* __restrict__ xbc = x + (size_t)bc * THW;
    float* __restrict__ obc       = out + (size_t)bc * THW;
    const int c = bc & 63;

    // block-uniform weight pointers: reads at use sites -> s_load from K$
    const float* __restrict__ wa = w1 + c * 27;     // [kt*9 + kh*3 + kw]
    const float* __restrict__ wb = w2 + c * 27;
    const float* __restrict__ wcc = w3 + c * 27;
    const float bias1 = b1[c], bias2 = b2[c], bias3 = b3[c];
    const float W0 = wm[0], W1 = wm[1], W2 = wm[2];
    const float goff = 0.5f * (W0 + W1 + W2);

    // 3 base voffsets (left/center/right); row offset r*224 folds into the
    // 12-bit imm. Row OOB (h-1<0 or h+1>=56) falls outside num_records=PLANE_B
    // (unsigned check) -> hardware returns 0. Col OOB forced via huge offset
    // (1<<30 + 448 stays OOB, no overflow).
    const int vmain  = (h - 1) * ROW_B + w * 4;
    const int vleft  = (w > 0)     ? vmain - 4 : (1 << 30);
    const int vright = (w < W - 1) ? vmain + 4 : (1 << 30);
    const int og4 = g * 4;

    const v4i osrd = make_srd(obc, THW * 4);

    // pending output accumulators (mod-indexed rings, all indices compile-time)
    float y1s[5], y2s[6], y3s[7];
#pragma unroll
    for (int i = 0; i < 5; ++i) y1s[i] = bias1;
#pragma unroll
    for (int i = 0; i < 6; ++i) y2s[i] = bias2;
#pragma unroll
    for (int i = 0; i < 7; ++i) y3s[i] = bias3;
    // lag-diff previous-y registers (zero-init matches "first k frames kept")
    float pv1 = 0.f, pv2[2] = {0.f, 0.f}, pv3[3] = {0.f, 0.f, 0.f};
    // 4-deep center-pixel pipeline: x[t,h,w] loaded at step t, used at step t+3
    float xc[4] = {0.f, 0.f, 0.f, 0.f};

    unroll_for<0, T + 3>([&](auto Pc) {
        constexpr int p = decltype(Pc)::value;
        if constexpr (p < T) {
            const v4i srd = make_srd(xbc + p * HW, PLANE_B);
            float v[3][3];
#pragma unroll
            for (int r = 0; r < 3; ++r) {
                v[r][0] = buf_load_f32(srd, vleft  + r * ROW_B, 0, 0);
                v[r][1] = buf_load_f32(srd, vmain  + r * ROW_B, 0, 0);
                v[r][2] = buf_load_f32(srd, vright + r * ROW_B, 0, 0);
            }

            // open new output slots (old occupants emitted 1+ steps ago)
            y1s[(p + 1) % 5] = bias1;   // output t=p+1
            y2s[(p + 2) % 6] = bias2;   // output t=p+2
            y3s[(p + 3) % 7] = bias3;   // output t=p+3

            auto tap = [&](float& acc, const float* __restrict__ wt) {
#pragma unroll
                for (int r = 0; r < 3; ++r)
#pragma unroll
                    for (int kw = 0; kw < 3; ++kw)
                        acc = fmaf(v[r][kw], wt[r * 3 + kw], acc);
            };
            // plane p contributes: kt=0 -> t=p+dil, kt=1 -> t=p, kt=2 -> t=p-dil
            tap(y1s[(p + 1) % 5], wa + 0);       // t=p+1
            tap(y1s[p % 5],       wa + 9);       // t=p
            tap(y1s[(p + 4) % 5], wa + 18);      // t=p-1 (p=0: dead slot)
            tap(y2s[(p + 2) % 6], wb + 0);       // t=p+2
            tap(y2s[p % 6],       wb + 9);       // t=p
            tap(y2s[(p + 4) % 6], wb + 18);      // t=p-2
            tap(y3s[(p + 3) % 7], wcc + 0);      // t=p+3
            tap(y3s[p % 7],       wcc + 9);      // t=p
            tap(y3s[(p + 4) % 7], wcc + 18);     // t=p-3 (= emission slot, last)

            xc[p % 4] = v[1][1];
        }
        if constexpr (p >= 3) {
            constexpr int t = p - 3;             // y3[t] just completed
            const float y1v = y1s[t % 5];
            const float y2v = y2s[t % 6];
            const float y3v = y3s[t % 7];
            const float d1 = y1v - pv1;          pv1 = y1v;
            const float d2 = y2v - pv2[t % 2];   pv2[t % 2] = y2v;
            const float d3 = y3v - pv3[t % 3];   pv3[t % 3] = y3v;
            const float gt = fmaf(sigm(d1), W0,
                             fmaf(sigm(d2), W1,
                             fmaf(sigm(d3), W2, -goff)));
            buf_store_f32(xc[t % 4] * gt, osrd, og4, t * PLANE_B, 0);
        }
    });
}

}  // namespace

extern "C" void kernel_launch(void* const* d_in, const int* in_sizes, int n_in,
                              void* d_out, int out_size, void* d_ws, size_t ws_size,
                              hipStream_t stream) {
    (void)in_sizes; (void)n_in; (void)d_ws; (void)ws_size; (void)out_size;
    const float* x  = (const float*)d_in[0];
    const float* w1 = (const float*)d_in[1];
    const float* b1 = (const float*)d_in[2];
    const float* w2 = (const float*)d_in[3];
    const float* b2 = (const float*)d_in[4];
    const float* w3 = (const float*)d_in[5];
    const float* b3 = (const float*)d_in[6];
    const float* wm = (const float*)d_in[7];
    float* out = (float*)d_out;

    // grid: x = ceil(3136 px / 256) = 13, y = 256 (b,c); block = 256 (4 waves).
    // 1 px/thread streaming form; bc in blockIdx.y keeps weights/biases on the
    // scalar path.
    tts_fused<<<dim3((HW + 255) / 256, 256), dim3(256), 0, stream>>>(
        x, w1, b1, w2, b2, w3, b3, wm, out);
}

// Round 8
// 293.328 us; speedup vs baseline: 1.2598x; 1.2598x over previous
//
#include <hip/hip_runtime.h>

namespace {

constexpr int T = 32, H = 56, W = 56;
constexpr int HW = H * W;           // 3136
constexpr int THW = T * HW;
constexpr int PLANE_B = HW * 4;     // 12544 bytes per plane
constexpr int ROW_B = W * 4;        // 224 bytes per row
constexpr int GROUPS = H * (W / 2); // 1568 two-pixel groups per (b,c)

template <int N> struct ic { static constexpr int value = N; };

typedef float v2f __attribute__((ext_vector_type(2)));
typedef int   v4i __attribute__((ext_vector_type(4)));

// Direct intrinsic bindings (compiler-tracked loads, auto waitcnt).
__device__ float buf_load_f32(v4i srd, int voff, int soff, int aux)
    __asm("llvm.amdgcn.raw.buffer.load.f32");
__device__ v2f buf_load_v2f(v4i srd, int voff, int soff, int aux)
    __asm("llvm.amdgcn.raw.buffer.load.v2f32");
__device__ void buf_store_v2f(v2f v, v4i srd, int voff, int soff, int aux)
    __asm("llvm.amdgcn.raw.buffer.store.v2f32");

__device__ __forceinline__ v4i make_srd(const void* p, int nrec) {
    v4i r;
    r.x = (int)(unsigned long long)p;
    r.y = (int)((unsigned long long)p >> 32);  // stride=0 in high half
    r.z = nrec;                                // num_records = BYTES
    r.w = 0x00020000;                          // raw untyped dword access
    return r;
}

__device__ __forceinline__ float sigm(float x) {
    // 1/(1+e^-x); fast native exp + rcp (rel err ~1e-6, threshold 1.9e-2)
    float e = __expf(-x);
    return __builtin_amdgcn_rcpf(1.0f + e);
}

// Proven structure (R1/R6: 140-147us, VGPR 84, zero spill): 7-plane register
// ring, 2 px/thread. This round keeps that structure and cuts instructions:
//  - SRD buffer loads (addressing verified correct in R7 incl. negative-voff
//    top halo wrap + 1<<30 col poison): row/col OOB -> HW returns 0; zero
//    cndmask, zero 64-bit address VALU in the loop.
//  - v_pk_fma_f32: rows cached as pairs (c0,c1),(c2,c3); kw=0/2 taps packed,
//    kw=1 scalar -> conv 162 -> ~114 ops/step.
// VGPR-budget law (R1-R7): compiler cap = 512/(2*min_waves); live set ~84-96
// with pair alignment -> pin 2 (cap 128). NEVER pin >= 4 (catastrophic spill).
__global__ __launch_bounds__(64, 2)
void tts_fused(const float* __restrict__ x,
               const float* __restrict__ w1, const float* __restrict__ b1,
               const float* __restrict__ w2, const float* __restrict__ b2,
               const float* __restrict__ w3, const float* __restrict__ b3,
               const float* __restrict__ wm,
               float* __restrict__ out) {
    const int g = blockIdx.x * 64 + threadIdx.x;
    if (g >= GROUPS) return;          // no barriers anywhere -> safe early exit
    const int bc = blockIdx.y;        // b*64 + c (block-uniform)
    const int h  = g / 28;            // 0..55
    const int wq = g - h * 28;        // 0..27
    const int w0 = wq << 1;           // 2 pixels per thread, 8B-aligned

    const float* __restrict__ xbc = x + (size_t)bc * THW;
    float* __restrict__ obc       = out + (size_t)bc * THW;
    const int c = bc & 63;
    const float* __restrict__ wa = w1 + c * 27;  // [kt*9 + kh*3 + kw]
    const float* __restrict__ wb = w2 + c * 27;
    const float* __restrict__ wc = w3 + c * 27;
    const float bias1 = b1[c], bias2 = b2[c], bias3 = b3[c];
    const float W0 = wm[0], W1 = wm[1], W2 = wm[2];
    const float goff = 0.5f * (W0 + W1 + W2);

    // Precomputed voffsets at row h-1. Row OOB: h=0 top row -> negative ->
    // unsigned-huge -> HW bounds fail -> 0 (verified R7). h=55 bottom row ->
    // offset >= PLANE_B -> 0. Col OOB: poison 1<<30 (stays OOB after +448 imm).
    const int voffC = (h - 1) * ROW_B + w0 * 4;
    const int voffL = (wq > 0)  ? voffC - 4 : (1 << 30);
    const int voffR = (wq < 27) ? voffC + 8 : (1 << 30);
    const int boff4 = (h * W + w0) * 4;
    const v4i osrd = make_srd(obc, THW * 4);

    // register ring: 7 planes (slot = plane mod 7) x 3 rows x 2 pairs
    // pair0 = (c0,c1) = cols (w0-1, w0); pair1 = (c2,c3) = cols (w0+1, w0+2)
    v2f cc[7][3][2];
    // lag-diff shift registers (packed: .x = px0, .y = px1)
    v2f p1v, p2a, p2b, p3a, p3b, p3c;
    p1v = 0.f; p2a = 0.f; p2b = 0.f; p3a = 0.f; p3b = 0.f; p3c = 0.f;

    auto zero_plane = [&](auto Sc) {
        constexpr int s = decltype(Sc)::value;
#pragma unroll
        for (int r = 0; r < 3; ++r) {
            cc[s][r][0] = 0.f; cc[s][r][1] = 0.f;
        }
    };

    auto load_plane = [&](auto Sc, int tp) {
        constexpr int s = decltype(Sc)::value;
        const v4i srd = make_srd(xbc + tp * HW, PLANE_B);  // uniform SALU only
#pragma unroll
        for (int r = 0; r < 3; ++r) {
            const float c0 = buf_load_f32(srd, voffL + r * ROW_B, 0, 0);
            const v2f   m  = buf_load_v2f(srd, voffC + r * ROW_B, 0, 0);
            const float c3 = buf_load_f32(srd, voffR + r * ROW_B, 0, 0);
            v2f q0; q0.x = c0;  q0.y = m.x;
            v2f q1; q1.x = m.y; q1.y = c3;
            cc[s][r][0] = q0; cc[s][r][1] = q1;
        }
    };

    auto conv9 = [&](v2f& acc, auto Sc, const float* __restrict__ wp) {
        constexpr int s = decltype(Sc)::value;
#pragma unroll
        for (int r = 0; r < 3; ++r) {
            const float wk0 = wp[r * 3 + 0];
            const float wk1 = wp[r * 3 + 1];
            const float wk2 = wp[r * 3 + 2];
            const v2f s0 = {wk0, wk0}, s2 = {wk2, wk2};
            acc = __builtin_elementwise_fma(cc[s][r][0], s0, acc);  // pk
            acc.x = fmaf(cc[s][r][0].y, wk1, acc.x);                // scalar
            acc.y = fmaf(cc[s][r][1].x, wk1, acc.y);                // scalar
            acc = __builtin_elementwise_fma(cc[s][r][1], s2, acc);  // pk
        }
    };

    // prologue: planes -3..-1 zero (slots 4,5,6); planes 0..2 loaded (0,1,2)
    zero_plane(ic<4>{}); zero_plane(ic<5>{}); zero_plane(ic<6>{});
    load_plane(ic<0>{}, 0); load_plane(ic<1>{}, 1); load_plane(ic<2>{}, 2);

    auto step = [&](int t, auto Uc) {   // requires t % 7 == Uc
        constexpr int u = decltype(Uc)::value;
        constexpr int snew = (u + 3) % 7;               // slot of plane t+3
        if (t + 3 < T) load_plane(ic<snew>{}, t + 3);
        else           zero_plane(ic<snew>{});

        v2f a1 = {bias1, bias1}, a2 = {bias2, bias2}, a3 = {bias3, bias3};

        conv9(a1, ic<(u + 6) % 7>{}, wa);       // plane t-1
        conv9(a1, ic<u>{},           wa + 9);   // plane t
        conv9(a1, ic<(u + 1) % 7>{}, wa + 18);  // plane t+1
        conv9(a2, ic<(u + 5) % 7>{}, wb);       // plane t-2
        conv9(a2, ic<u>{},           wb + 9);   // plane t
        conv9(a2, ic<(u + 2) % 7>{}, wb + 18);  // plane t+2
        conv9(a3, ic<(u + 4) % 7>{}, wc);       // plane t-3
        conv9(a3, ic<u>{},           wc + 9);   // plane t
        conv9(a3, ic<(u + 3) % 7>{}, wc + 18);  // plane t+3 (fresh) LAST

        // packed lag diffs
        const v2f d1 = (t >= 1) ? a1 - p1v : a1;
        const v2f d2 = (t >= 2) ? a2 - p2b : a2;
        const v2f d3 = (t >= 3) ? a3 - p3c : a3;
        p1v = a1;
        p2b = p2a; p2a = a2;
        p3c = p3b; p3b = p3a; p3a = a3;

        v2f ov;
        ov.x = cc[u][1][0].y * fmaf(sigm(d1.x), W0,
                               fmaf(sigm(d2.x), W1,
                               fmaf(sigm(d3.x), W2, -goff)));
        ov.y = cc[u][1][1].x * fmaf(sigm(d1.y), W0,
                               fmaf(sigm(d2.y), W1,
                               fmaf(sigm(d3.y), W2, -goff)));
        buf_store_v2f(ov, osrd, boff4, t * PLANE_B, 0);
    };

#pragma unroll 1
    for (int tb = 0; tb <= T - 7; tb += 7) {    // tb = 0,7,14,21 (tb%7==0)
        step(tb + 0, ic<0>{}); step(tb + 1, ic<1>{}); step(tb + 2, ic<2>{});
        step(tb + 3, ic<3>{}); step(tb + 4, ic<4>{}); step(tb + 5, ic<5>{});
        step(tb + 6, ic<6>{});
    }
    // remainder: t = 28..31 (28 % 7 == 0)
    step(28, ic<0>{}); step(29, ic<1>{}); step(30, ic<2>{}); step(31, ic<3>{});
}

}  // namespace

extern "C" void kernel_launch(void* const* d_in, const int* in_sizes, int n_in,
                              void* d_out, int out_size, void* d_ws, size_t ws_size,
                              hipStream_t stream) {
    (void)in_sizes; (void)n_in; (void)d_ws; (void)ws_size; (void)out_size;
    const float* x  = (const float*)d_in[0];
    const float* w1 = (const float*)d_in[1];
    const float* b1 = (const float*)d_in[2];
    const float* w2 = (const float*)d_in[3];
    const float* b2 = (const float*)d_in[4];
    const float* w3 = (const float*)d_in[5];
    const float* b3 = (const float*)d_in[6];
    const float* wm = (const float*)d_in[7];
    float* out = (float*)d_out;

    // grid: x = ceil(1568/64) = 25, y = 256 (b,c); block = 1 wave (R1 geometry,
    // best measured). bc in blockIdx.y keeps weights/biases on the scalar path.
    tts_fused<<<dim3((GROUPS + 63) / 64, 256), dim3(64), 0, stream>>>(
        x, w1, b1, w2, b2, w3, b3, wm, out);
}